// Round 2
// baseline (17.804 us; speedup 1.0000x reference)
//
#include <hip/hip_runtime.h>
#include <math.h>

// Problem constants: B=256, D=784, H=512
#define BATCH 256
#define DD    784
#define HH    512
#define DT    64              // d-tile width (= lanes per wave)
#define NT    13              // ceil(DD/DT)
#define RR    16              // batch replicas per d-tile
#define BR    (BATCH / RR)    // 16 batch rows per block
#define BLK   1024            // threads per block
#define NW    (BLK / 64)      // 16 waves per block
#define HCH   (HH / NW)       // 32 h's per wave in phase 1

__device__ __forceinline__ float sigmoidf_(float a) {
    return 1.0f / (1.0f + __expf(-a));
}

// Block (r, dt): phase 1 computes L0/L1 for its 64-d tile (lane = d, so the
// W read is a coalesced 256B wave-load and the reduction over h is per-lane
// serial — no shuffles). Phase 2: wave = batch row, lane = d → coalesced
// x read and out write.
__global__ __launch_bounds__(BLK) void nade_fused(
    const float* __restrict__ x,    // (B, D)
    const float* __restrict__ V,    // (D, H)
    const float* __restrict__ bvec, // (D,)
    const float* __restrict__ W,    // (H, D)
    const float* __restrict__ c,    // (1, H)
    float* __restrict__ out)        // (B, D)
{
    const int blk  = blockIdx.x;
    const int dt   = blk % NT;
    const int r    = blk / NT;
    const int t    = threadIdx.x;
    const int lane = t & 63;
    const int wave = t >> 6;          // 0..15

    const int  d_raw = dt * DT + lane;
    const bool dval  = (d_raw < DD);
    const int  d     = dval ? d_raw : (DD - 1);   // clamp for loads only

    // ---- Phase 1: per-lane accumulation over this wave's 32 h's ----
    const int h0 = wave * HCH;
    float p0 = 0.f, q0 = 0.f, p1 = 0.f, q1 = 0.f;
    const float* Vrow = V + (size_t)d * HH;

    #pragma unroll
    for (int i = 0; i < HCH; i += 4) {
        const float4 v4 = *reinterpret_cast<const float4*>(Vrow + h0 + i);
        const float vv[4] = {v4.x, v4.y, v4.z, v4.w};
        #pragma unroll
        for (int j = 0; j < 4; ++j) {
            const int   hh = h0 + i + j;
            const float ch = c[hh];
            const float s0 = sigmoidf_(ch);
            const float w  = W[hh * DD + d];    // coalesced: lanes -> consecutive d
            const float s1 = sigmoidf_(w + ch);
            const float ds = s1 - s0;
            p0 += s0 * vv[j];
            q0 += s0;
            p1 += ds * vv[j];
            q1 += ds;
        }
    }

    // ---- Cross-wave reduce (16 partials per d) ----
    __shared__ float red[NW][DT][4];
    red[wave][lane][0] = p0;
    red[wave][lane][1] = q0;
    red[wave][lane][2] = p1;
    red[wave][lane][3] = q1;
    __syncthreads();

    __shared__ float L0s[DT], L1s[DT];
    if (t < DT * 4) {
        const int dl = t & 63;
        const int m  = t >> 6;        // metric 0..3
        float s = 0.f;
        #pragma unroll
        for (int w2 = 0; w2 < NW; ++w2) s += red[w2][dl][m];
        red[0][dl][m] = s;            // only this thread touches [dl][m]
    }
    __syncthreads();
    if (t < DT) {
        const int dr = dt * DT + t;
        const float bd = bvec[(dr < DD) ? dr : (DD - 1)];
        L0s[t] = red[0][t][0] + bd * red[0][t][1];   // L0[d]
        L1s[t] = red[0][t][2] + bd * red[0][t][3];   // L1[d]
    }
    __syncthreads();

    // ---- Phase 2: wave = batch row (16 rows per block), lane = d ----
    const float L0 = L0s[lane];
    const float L1 = L1s[lane];
    const int   b  = r * BR + wave;
    if (dval) {
        float xv = 0.f;
        if (d_raw >= 1) xv = x[(size_t)b * DD + (d_raw - 1)];  // coalesced
        out[(size_t)b * DD + d_raw] = sigmoidf_(L0 + xv * L1); // coalesced
    }
}

extern "C" void kernel_launch(void* const* d_in, const int* in_sizes, int n_in,
                              void* d_out, int out_size, void* d_ws, size_t ws_size,
                              hipStream_t stream) {
    const float* x    = (const float*)d_in[0]; // (256, 784)
    const float* V    = (const float*)d_in[1]; // (784, 512)
    const float* bvec = (const float*)d_in[2]; // (784,)
    const float* W    = (const float*)d_in[3]; // (512, 784)
    const float* c    = (const float*)d_in[4]; // (1, 512)
    float* out = (float*)d_out;                // (256, 784)

    nade_fused<<<NT * RR, BLK, 0, stream>>>(x, V, bvec, W, c, out);
}

// Round 3
// 10.602 us; speedup vs baseline: 1.6794x; 1.6794x over previous
//
#include <hip/hip_runtime.h>

// B=256, D=784, H=512
#define BATCH 256
#define DD    784
#define HH    512
#define DPB   16              // d's per block
#define NBLK  (DD / DPB)      // 49
#define BLK   1024
#define NW    (BLK / 64)      // 16 waves = 16 d's

__device__ __forceinline__ float sigmoidf_(float a) {
    return 1.0f / (1.0f + __expf(-a));
}

// Collapsed NADE (x is exactly binary):
//   out[b,d] = sigmoid(L0[d] + x[b,d-1]*L1[d])
//   L0[d] = sum_h sigmoid(c[h]) * (V[d,h]+b[d])
//   L1[d] = sum_h (sigmoid(W[h,d-1]+c[h]) - sigmoid(c[h])) * (V[d,h]+b[d])
__global__ __launch_bounds__(BLK) void nade_fused(
    const float* __restrict__ x,    // (B, D)
    const float* __restrict__ V,    // (D, H)
    const float* __restrict__ bvec, // (D,)
    const float* __restrict__ W,    // (H, D)
    const float* __restrict__ c,    // (1, H)
    float* __restrict__ out)        // (B, D)
{
    __shared__ float Wl[DPB][HH];   // 32 KB; Wl[col][h'] holds W[h, d0-1+col], h' = h ^ 4*(col&7)
    __shared__ float L0s[DPB], L1s[DPB];

    const int d0 = blockIdx.x * DPB;
    const int t  = threadIdx.x;

    // ---- Stage W cols [d0-1 .. d0+14] (coalesced global; swizzled LDS, 2-way banks) ----
    #pragma unroll
    for (int i = 0; i < 8; ++i) {
        const int idx = t + i * BLK;        // 0..8191
        const int h   = idx >> 4;           // 0..511
        const int col = idx & 15;           // 0..15
        int gd = d0 - 1 + col;
        if (gd < 0) gd = 0;                 // block 0, col 0: value never used (d=0 has no W term)
        Wl[col][h ^ (4 * (col & 7))] = W[(size_t)h * DD + gd];
    }
    __syncthreads();

    // ---- Phase 1: wave = local d, lane covers h = 4*lane + j + 256*k ----
    const int wave = t >> 6;
    const int lane = t & 63;
    const int d    = d0 + wave;
    const float bd = bvec[d];

    float a0 = 0.f, a1 = 0.f;               // L0, L1 partials (b folded in)
    #pragma unroll
    for (int k = 0; k < 2; ++k) {
        const int hb    = 4 * lane + 256 * k;
        const int chunk = (lane + 64 * k) ^ (wave & 7);   // swizzled float4 index
        const float4 v4 = *reinterpret_cast<const float4*>(V + (size_t)d * HH + hb);
        const float4 c4 = *reinterpret_cast<const float4*>(c + hb);
        const float4 w4 = *reinterpret_cast<const float4*>(&Wl[wave][4 * chunk]);
        const float vv[4] = {v4.x, v4.y, v4.z, v4.w};
        const float cc[4] = {c4.x, c4.y, c4.z, c4.w};
        const float ww[4] = {w4.x, w4.y, w4.z, w4.w};
        #pragma unroll
        for (int j = 0; j < 4; ++j) {
            const float s0 = sigmoidf_(cc[j]);
            const float s1 = sigmoidf_(ww[j] + cc[j]);   // uses W[h, d-1]
            const float vb = vv[j] + bd;
            a0 += s0 * vb;
            a1 += (s1 - s0) * vb;
        }
    }
    #pragma unroll
    for (int off = 32; off > 0; off >>= 1) {
        a0 += __shfl_down(a0, off);
        a1 += __shfl_down(a1, off);
    }
    if (lane == 0) {
        L0s[wave] = a0;
        L1s[wave] = a1;
    }
    __syncthreads();

    // ---- Phase 2: thread = (batch row, d-quad); full-line coalesced stores ----
    const int b     = t >> 2;       // 0..255
    const int quad  = t & 3;        // 0..3
    const int dbase = d0 + 4 * quad;
    float o[4];
    #pragma unroll
    for (int j = 0; j < 4; ++j) {
        const int dr = dbase + j;
        float xv = 0.f;
        if (dr >= 1) xv = x[(size_t)b * DD + dr - 1];
        o[j] = sigmoidf_(L0s[4 * quad + j] + xv * L1s[4 * quad + j]);
    }
    *reinterpret_cast<float4*>(out + (size_t)b * DD + dbase) =
        make_float4(o[0], o[1], o[2], o[3]);
}

extern "C" void kernel_launch(void* const* d_in, const int* in_sizes, int n_in,
                              void* d_out, int out_size, void* d_ws, size_t ws_size,
                              hipStream_t stream) {
    const float* x    = (const float*)d_in[0]; // (256, 784)
    const float* V    = (const float*)d_in[1]; // (784, 512)
    const float* bvec = (const float*)d_in[2]; // (784,)
    const float* W    = (const float*)d_in[3]; // (512, 784)
    const float* c    = (const float*)d_in[4]; // (1, 512)
    float* out = (float*)d_out;                // (256, 784)

    nade_fused<<<NBLK, BLK, 0, stream>>>(x, V, bvec, W, c, out);
}

// Round 4
// 10.157 us; speedup vs baseline: 1.7529x; 1.0438x over previous
//
#include <hip/hip_runtime.h>

// B=256, D=784, H=512
#define BATCH 256
#define DD    784
#define HH    512
#define DPB   16              // d's per block
#define NBLK  (DD / DPB)      // 49
#define BLK   1024
#define NW    (BLK / 64)      // 16 waves = 16 d's

__device__ __forceinline__ float sigmoidf_(float a) {
    return 1.0f / (1.0f + __expf(-a));
}

// Collapsed NADE (x is exactly binary 0.0/1.0):
//   out[b,d] = sigmoid(L0[d] + x[b,d-1]*L1[d])
//   L0[d] = sum_h sigmoid(c[h]) * (V[d,h]+b[d])
//   L1[d] = sum_h (sigmoid(W[h,d-1]+c[h]) - sigmoid(c[h])) * (V[d,h]+b[d])
__global__ __launch_bounds__(BLK) void nade_fused(
    const float* __restrict__ x,    // (B, D)
    const float* __restrict__ V,    // (D, H)
    const float* __restrict__ bvec, // (D,)
    const float* __restrict__ W,    // (H, D)
    const float* __restrict__ c,    // (1, H)
    float* __restrict__ out)        // (B, D)
{
    __shared__ float Wl[DPB][HH];   // 32 KB; Wl[col][h'] = W[h, d0-1+col], h' = h ^ 4*(col&7)
    __shared__ float L0s[DPB], L1s[DPB];

    const int d0 = blockIdx.x * DPB;
    const int t  = threadIdx.x;
    const int wave = t >> 6;
    const int lane = t & 63;

    // ================= PREFETCH: issue every global load up front =================
    // (all addresses known at entry; maximizes bytes-in-flight per block)

    // -- W staging addresses (8 scalar loads) --
    float wreg[8];
    int   wdst[8];
    #pragma unroll
    for (int i = 0; i < 8; ++i) {
        const int idx = t + i * BLK;        // 0..8191
        const int h   = idx >> 4;           // 0..511
        const int col = idx & 15;           // 0..15
        int gd = d0 - 1 + col;
        if (gd < 0) gd = 0;                 // block 0, col 0: value never used (d=0 has no W term)
        wreg[i] = W[(size_t)h * DD + gd];
        wdst[i] = col * HH + (h ^ (4 * (col & 7)));
    }

    // -- phase-1 operands: V row (wave's d), c --
    const int d    = d0 + wave;
    const float bd = bvec[d];
    float4 v4[2], c4[2];
    #pragma unroll
    for (int k = 0; k < 2; ++k) {
        const int hb = 4 * lane + 256 * k;
        v4[k] = *reinterpret_cast<const float4*>(V + (size_t)d * HH + hb);
        c4[k] = *reinterpret_cast<const float4*>(c + hb);
    }

    // -- phase-2 operands: x[b, dbase-1 .. dbase+2] --
    const int b     = t >> 2;       // 0..255
    const int quad  = t & 3;        // 0..3
    const int dbase = d0 + 4 * quad;
    const float  xs = x[(size_t)b * DD + ((dbase >= 1) ? (dbase - 1) : 0)];
    const float4 xq = *reinterpret_cast<const float4*>(x + (size_t)b * DD + dbase);

    // ================= STAGE W to LDS (transposed, swizzled) =================
    #pragma unroll
    for (int i = 0; i < 8; ++i)
        (&Wl[0][0])[wdst[i]] = wreg[i];
    __syncthreads();

    // ================= PHASE 1: wave = d, lane = h-quad =================
    float a0 = 0.f, a1 = 0.f;
    #pragma unroll
    for (int k = 0; k < 2; ++k) {
        const int chunk = (lane + 64 * k) ^ (wave & 7);   // swizzled float4 index
        const float4 w4 = *reinterpret_cast<const float4*>(&Wl[wave][4 * chunk]);
        const float vv[4] = {v4[k].x, v4[k].y, v4[k].z, v4[k].w};
        const float cc[4] = {c4[k].x, c4[k].y, c4[k].z, c4[k].w};
        const float ww[4] = {w4.x, w4.y, w4.z, w4.w};
        #pragma unroll
        for (int j = 0; j < 4; ++j) {
            const float s0 = sigmoidf_(cc[j]);
            const float s1 = sigmoidf_(ww[j] + cc[j]);   // uses W[h, d-1]
            const float vb = vv[j] + bd;
            a0 += s0 * vb;
            a1 += (s1 - s0) * vb;
        }
    }
    #pragma unroll
    for (int off = 32; off > 0; off >>= 1) {
        a0 += __shfl_down(a0, off);
        a1 += __shfl_down(a1, off);
    }
    if (lane == 0) {
        L0s[wave] = a0;
        L1s[wave] = a1;
    }
    __syncthreads();

    // ================= PHASE 2: thread = (batch row, d-quad) =================
    float o[4];
    const float xv[4] = {xs, xq.x, xq.y, xq.z};
    #pragma unroll
    for (int j = 0; j < 4; ++j) {
        const int dr = dbase + j;
        const float xu = (dr >= 1) ? xv[j] : 0.0f;
        o[j] = sigmoidf_(L0s[4 * quad + j] + xu * L1s[4 * quad + j]);
    }
    *reinterpret_cast<float4*>(out + (size_t)b * DD + dbase) =
        make_float4(o[0], o[1], o[2], o[3]);
}

extern "C" void kernel_launch(void* const* d_in, const int* in_sizes, int n_in,
                              void* d_out, int out_size, void* d_ws, size_t ws_size,
                              hipStream_t stream) {
    const float* x    = (const float*)d_in[0]; // (256, 784)
    const float* V    = (const float*)d_in[1]; // (784, 512)
    const float* bvec = (const float*)d_in[2]; // (784,)
    const float* W    = (const float*)d_in[3]; // (512, 784)
    const float* c    = (const float*)d_in[4]; // (1, 512)
    float* out = (float*)d_out;                // (256, 784)

    nade_fused<<<NBLK, BLK, 0, stream>>>(x, V, bvec, W, c, out);
}